// Round 2
// baseline (150.380 us; speedup 1.0000x reference)
//
#include <hip/hip_runtime.h>
#include <stdint.h>

// ---- JAX threefry config reproduction ----
// MODE 1 = jax_threefry_partitionable=True (default since JAX 0.5):
//   split:  subkey[j] = threefry(key, hi=0, lo=j)   (foldlike, full pair)
//   bits:   bits[i]   = o0 ^ o1 of threefry(subkey, hi=0, lo=i)
// MODE 0 = original scheme (both split and bits use iota halves-split).
#define JAX_MODE_PARTITIONABLE 1

#define R_DIM 16
#define C_DIM 16
#define COUT_DIM 64
#define CIN_DIM 16
#define KH_DIM 8
#define KW_DIM 8
#define N_TOTAL (R_DIM * C_DIM * COUT_DIM * CIN_DIM * KH_DIM * KW_DIM) // 16777216
#define N_HALF (N_TOTAL / 2)
#define Y_SIZE (COUT_DIM * R_DIM * C_DIM) // 16384
#define X_SIZE (CIN_DIM * KH_DIM * KW_DIM) // 1024

struct U2 { uint32_t a, b; };

__host__ __device__ constexpr uint32_t rotl32(uint32_t x, int r) {
  return (x << r) | (x >> (32 - r));
}

// JAX threefry_2x32 (20 rounds), matches jax/_src/prng.py exactly.
__host__ __device__ constexpr U2 threefry2x32(uint32_t k0, uint32_t k1,
                                              uint32_t x0, uint32_t x1) {
  uint32_t ks2 = k0 ^ k1 ^ 0x1BD11BDAu;
  x0 += k0; x1 += k1;
  // i=0 rotations [13,15,26,6]
  x0 += x1; x1 = rotl32(x1, 13); x1 ^= x0;
  x0 += x1; x1 = rotl32(x1, 15); x1 ^= x0;
  x0 += x1; x1 = rotl32(x1, 26); x1 ^= x0;
  x0 += x1; x1 = rotl32(x1, 6);  x1 ^= x0;
  x0 += k1; x1 += ks2 + 1u;
  // i=1 rotations [17,29,16,24]
  x0 += x1; x1 = rotl32(x1, 17); x1 ^= x0;
  x0 += x1; x1 = rotl32(x1, 29); x1 ^= x0;
  x0 += x1; x1 = rotl32(x1, 16); x1 ^= x0;
  x0 += x1; x1 = rotl32(x1, 24); x1 ^= x0;
  x0 += ks2; x1 += k0 + 2u;
  // i=2 rotations [13,15,26,6]
  x0 += x1; x1 = rotl32(x1, 13); x1 ^= x0;
  x0 += x1; x1 = rotl32(x1, 15); x1 ^= x0;
  x0 += x1; x1 = rotl32(x1, 26); x1 ^= x0;
  x0 += x1; x1 = rotl32(x1, 6);  x1 ^= x0;
  x0 += k0; x1 += k1 + 3u;
  // i=3 rotations [17,29,16,24]
  x0 += x1; x1 = rotl32(x1, 17); x1 ^= x0;
  x0 += x1; x1 = rotl32(x1, 29); x1 ^= x0;
  x0 += x1; x1 = rotl32(x1, 16); x1 ^= x0;
  x0 += x1; x1 = rotl32(x1, 24); x1 ^= x0;
  x0 += k1; x1 += ks2 + 4u;
  // i=4 rotations [13,15,26,6]
  x0 += x1; x1 = rotl32(x1, 13); x1 ^= x0;
  x0 += x1; x1 = rotl32(x1, 15); x1 ^= x0;
  x0 += x1; x1 = rotl32(x1, 26); x1 ^= x0;
  x0 += x1; x1 = rotl32(x1, 6);  x1 ^= x0;
  x0 += ks2; x1 += k0 + 5u;
  return {x0, x1};
}

#if JAX_MODE_PARTITIONABLE
// foldlike split: subkey[j] = full pair of threefry(key, 0, j)
constexpr U2 SK1 = threefry2x32(0u, 42u, 0u, 0u); // -> bern_plus
constexpr U2 SK2 = threefry2x32(0u, 42u, 0u, 1u); // -> bern_minus
constexpr U2 SK3 = threefry2x32(0u, 42u, 0u, 2u); // -> F_minus_raw
constexpr U2 SK4 = threefry2x32(0u, 42u, 0u, 3u); // -> F_plus_raw
constexpr U2 SK5 = threefry2x32(0u, 42u, 0u, 4u); // -> umin
#else
// original split: threefry over counts iota(10), halves-split, reshape (5,2)
constexpr U2 S0 = threefry2x32(0u, 42u, 0u, 5u);
constexpr U2 S1 = threefry2x32(0u, 42u, 1u, 6u);
constexpr U2 S2 = threefry2x32(0u, 42u, 2u, 7u);
constexpr U2 S3 = threefry2x32(0u, 42u, 3u, 8u);
constexpr U2 S4 = threefry2x32(0u, 42u, 4u, 9u);
constexpr U2 SK1 = {S0.a, S1.a};
constexpr U2 SK2 = {S2.a, S3.a};
constexpr U2 SK3 = {S4.a, S0.b};
constexpr U2 SK4 = {S1.b, S2.b};
constexpr U2 SK5 = {S3.b, S4.b};
#endif

__device__ __forceinline__ float bits_to_unit_float(uint32_t bits) {
  uint32_t fb = (bits >> 9) | 0x3f800000u;
  return __uint_as_float(fb) - 1.0f;
}

__device__ __forceinline__ float probs_plus_of(bool A, bool B, bool Cg) {
  return (!A && B) ? 0.032f : ((!A && !B && !Cg) ? 0.102f : 0.0f);
}
__device__ __forceinline__ float probs_minus_of(bool A, bool B, bool Cg) {
  return (A && !B) ? 0.96f : ((!A && !B && Cg) ? 0.051f : 0.0f);
}

__device__ __forceinline__ float update_weight(float wv, float pp, float pm,
                                               float u1, float u2, float u3,
                                               float u4, float u5) {
  const float inv7 = (float)(1.0 / 7.0);
  bool bp = u1 < pp;
  bool bm = u2 < pm;
  float ratio = __fmul_rn(wv, inv7);
  float pFm = __fmul_rn(__fsub_rn(1.0f, ratio), __fadd_rn(1.0f, ratio));
  float pFp = __fmul_rn(ratio, __fsub_rn(2.0f, ratio));
  bool Fm = u3 < pFm;
  bool Fp = u4 < pFp;
  bool um = u5 < 0.008f;
  float fplus = (Fp || um) ? 1.0f : 0.0f;
  float fminus = (Fm || um) ? 1.0f : 0.0f;
  float nw = wv + (bp ? fplus : 0.0f) - (bm ? fminus : 0.0f);
  return fminf(fmaxf(nw, 0.0f), 7.0f);
}

// ---------- precompute x_times (1024) and y_times (16384) ----------
__global__ void precompute_times(const int* __restrict__ in_sp,
                                 const int* __restrict__ out_sp,
                                 int* __restrict__ xt, int* __restrict__ yt) {
  int tid = blockIdx.x * 256 + threadIdx.x;
  if (tid < Y_SIZE) {
    int s = 0;
#pragma unroll
    for (int t = 0; t < 7; ++t) s += out_sp[t * Y_SIZE + tid];
    yt[tid] = 7 - s;
  } else if (tid < Y_SIZE + X_SIZE) {
    int j = tid - Y_SIZE;
    int s = 0;
#pragma unroll
    for (int t = 0; t < 7; ++t) s += in_sp[t * X_SIZE + j];
    xt[j] = 7 - s;
  }
}

#if JAX_MODE_PARTITIONABLE
// ---------- main kernel, partitionable bits: one element per thread ----------
__global__ __launch_bounds__(256) void modstdp_part(const float* __restrict__ w,
                                                    const int* __restrict__ xt,
                                                    const int* __restrict__ yt,
                                                    float* __restrict__ out) {
  uint32_t i = blockIdx.x * 256u + threadIdx.x;
  float wv = w[i];
  int bx = xt[i & 1023u];
  uint32_t cout = (i >> 10) & 63u;
  uint32_t c = (i >> 16) & 15u;
  uint32_t r = i >> 20;
  int by = yt[cout * 256u + r * 16u + c];
  bool A = (bx == 7), B = (by == 7), Cg = (bx > by);
  float pp = probs_plus_of(A, B, Cg);
  float pm = probs_minus_of(A, B, Cg);

  U2 o1 = threefry2x32(SK1.a, SK1.b, 0u, i);
  U2 o2 = threefry2x32(SK2.a, SK2.b, 0u, i);
  U2 o3 = threefry2x32(SK3.a, SK3.b, 0u, i);
  U2 o4 = threefry2x32(SK4.a, SK4.b, 0u, i);
  U2 o5 = threefry2x32(SK5.a, SK5.b, 0u, i);
  float u1 = bits_to_unit_float(o1.a ^ o1.b);
  float u2 = bits_to_unit_float(o2.a ^ o2.b);
  float u3 = bits_to_unit_float(o3.a ^ o3.b);
  float u4 = bits_to_unit_float(o4.a ^ o4.b);
  float u5 = bits_to_unit_float(o5.a ^ o5.b);

  out[i] = update_weight(wv, pp, pm, u1, u2, u3, u4, u5);
}
#else
// ---------- main kernel, original bits: one (i, i+N/2) pair per thread ----------
__global__ __launch_bounds__(256) void modstdp_orig(const float* __restrict__ w,
                                                    const int* __restrict__ xt,
                                                    const int* __restrict__ yt,
                                                    float* __restrict__ out) {
  uint32_t i = blockIdx.x * 256u + threadIdx.x; // i < N_HALF, pairs with i+N_HALF
  uint32_t j = i + (uint32_t)N_HALF;
  float w0 = w[i], w1 = w[j];
  int bx = xt[i & 1023u];
  uint32_t cout = (i >> 10) & 63u;
  uint32_t c = (i >> 16) & 15u;
  uint32_t r = i >> 20; // r in [0,8); pair has r+8
  int by0 = yt[cout * 256u + r * 16u + c];
  int by1 = yt[cout * 256u + (r + 8u) * 16u + c];
  bool A = (bx == 7);
  bool B0 = (by0 == 7), Cg0 = (bx > by0);
  bool B1 = (by1 == 7), Cg1 = (bx > by1);
  float pp0 = probs_plus_of(A, B0, Cg0), pm0 = probs_minus_of(A, B0, Cg0);
  float pp1 = probs_plus_of(A, B1, Cg1), pm1 = probs_minus_of(A, B1, Cg1);

  U2 o1 = threefry2x32(SK1.a, SK1.b, i, j);
  U2 o2 = threefry2x32(SK2.a, SK2.b, i, j);
  U2 o3 = threefry2x32(SK3.a, SK3.b, i, j);
  U2 o4 = threefry2x32(SK4.a, SK4.b, i, j);
  U2 o5 = threefry2x32(SK5.a, SK5.b, i, j);

  out[i] = update_weight(w0, pp0, pm0,
                         bits_to_unit_float(o1.a), bits_to_unit_float(o2.a),
                         bits_to_unit_float(o3.a), bits_to_unit_float(o4.a),
                         bits_to_unit_float(o5.a));
  out[j] = update_weight(w1, pp1, pm1,
                         bits_to_unit_float(o1.b), bits_to_unit_float(o2.b),
                         bits_to_unit_float(o3.b), bits_to_unit_float(o4.b),
                         bits_to_unit_float(o5.b));
}
#endif

extern "C" void kernel_launch(void* const* d_in, const int* in_sizes, int n_in,
                              void* d_out, int out_size, void* d_ws, size_t ws_size,
                              hipStream_t stream) {
  const float* w = (const float*)d_in[0];
  const int* isp = (const int*)d_in[1];
  const int* osp = (const int*)d_in[2];
  float* out = (float*)d_out;
  int* xt = (int*)d_ws;            // 1024 ints
  int* yt = ((int*)d_ws) + X_SIZE; // 16384 ints

  precompute_times<<<(Y_SIZE + X_SIZE + 255) / 256, 256, 0, stream>>>(isp, osp, xt, yt);
#if JAX_MODE_PARTITIONABLE
  modstdp_part<<<N_TOTAL / 256, 256, 0, stream>>>(w, xt, yt, out);
#else
  modstdp_orig<<<N_HALF / 256, 256, 0, stream>>>(w, xt, yt, out);
#endif
}

// Round 3
// 148.899 us; speedup vs baseline: 1.0099x; 1.0099x over previous
//
#include <hip/hip_runtime.h>
#include <stdint.h>

// JAX reproduction: jax_threefry_partitionable=True (default since JAX 0.5):
//   split:  subkey[j] = threefry(key, hi=0, lo=j)   (foldlike, full pair)
//   bits:   bits[i]   = o0 ^ o1 of threefry(subkey, hi=0, lo=i)
// Verified bit-exact in R2 (absmax 0.0).

#define R_DIM 16
#define C_DIM 16
#define COUT_DIM 64
#define CIN_DIM 16
#define KH_DIM 8
#define KW_DIM 8
#define N_TOTAL (R_DIM * C_DIM * COUT_DIM * CIN_DIM * KH_DIM * KW_DIM) // 16777216
#define Y_SIZE (COUT_DIM * R_DIM * C_DIM) // 16384
#define X_SIZE (CIN_DIM * KH_DIM * KW_DIM) // 1024

struct U2 { uint32_t a, b; };

// ---------- constexpr threefry (compile-time key derivation) ----------
constexpr uint32_t rotl_c(uint32_t x, int r) {
  return (x << r) | (x >> (32 - r));
}

constexpr U2 threefry_c(uint32_t k0, uint32_t k1, uint32_t x0, uint32_t x1) {
  uint32_t ks2 = k0 ^ k1 ^ 0x1BD11BDAu;
  x0 += k0; x1 += k1;
  x0 += x1; x1 = rotl_c(x1, 13); x1 ^= x0;
  x0 += x1; x1 = rotl_c(x1, 15); x1 ^= x0;
  x0 += x1; x1 = rotl_c(x1, 26); x1 ^= x0;
  x0 += x1; x1 = rotl_c(x1, 6);  x1 ^= x0;
  x0 += k1; x1 += ks2 + 1u;
  x0 += x1; x1 = rotl_c(x1, 17); x1 ^= x0;
  x0 += x1; x1 = rotl_c(x1, 29); x1 ^= x0;
  x0 += x1; x1 = rotl_c(x1, 16); x1 ^= x0;
  x0 += x1; x1 = rotl_c(x1, 24); x1 ^= x0;
  x0 += ks2; x1 += k0 + 2u;
  x0 += x1; x1 = rotl_c(x1, 13); x1 ^= x0;
  x0 += x1; x1 = rotl_c(x1, 15); x1 ^= x0;
  x0 += x1; x1 = rotl_c(x1, 26); x1 ^= x0;
  x0 += x1; x1 = rotl_c(x1, 6);  x1 ^= x0;
  x0 += k0; x1 += k1 + 3u;
  x0 += x1; x1 = rotl_c(x1, 17); x1 ^= x0;
  x0 += x1; x1 = rotl_c(x1, 29); x1 ^= x0;
  x0 += x1; x1 = rotl_c(x1, 16); x1 ^= x0;
  x0 += x1; x1 = rotl_c(x1, 24); x1 ^= x0;
  x0 += k1; x1 += ks2 + 4u;
  x0 += x1; x1 = rotl_c(x1, 13); x1 ^= x0;
  x0 += x1; x1 = rotl_c(x1, 15); x1 ^= x0;
  x0 += x1; x1 = rotl_c(x1, 26); x1 ^= x0;
  x0 += x1; x1 = rotl_c(x1, 6);  x1 ^= x0;
  x0 += ks2; x1 += k0 + 5u;
  return {x0, x1};
}

// foldlike split of key(42): subkey[j] = full pair of threefry(0, 42, 0, j)
constexpr U2 SK1 = threefry_c(0u, 42u, 0u, 0u); // -> bern_plus
constexpr U2 SK2 = threefry_c(0u, 42u, 0u, 1u); // -> bern_minus
constexpr U2 SK3 = threefry_c(0u, 42u, 0u, 2u); // -> F_minus_raw
constexpr U2 SK4 = threefry_c(0u, 42u, 0u, 3u); // -> F_plus_raw
constexpr U2 SK5 = threefry_c(0u, 42u, 0u, 4u); // -> umin

// ---------- device threefry: force v_alignbit_b32 for rotations ----------
__device__ __forceinline__ uint32_t rotl_d(uint32_t x, int r) {
  // alignbit(s0,s1,sh) = ((u64(s0)<<32)|s1) >> (sh&31); s0=s1=x, sh=32-r -> rotl(x,r)
  return __builtin_amdgcn_alignbit(x, x, 32 - r);
}

__device__ __forceinline__ uint32_t threefry_fold_d(uint32_t k0, uint32_t k1,
                                                    uint32_t x1_in) {
  uint32_t ks2 = k0 ^ k1 ^ 0x1BD11BDAu;
  uint32_t x0 = k0;           // 0 + k0
  uint32_t x1 = x1_in + k1;
  x0 += x1; x1 = rotl_d(x1, 13); x1 ^= x0;
  x0 += x1; x1 = rotl_d(x1, 15); x1 ^= x0;
  x0 += x1; x1 = rotl_d(x1, 26); x1 ^= x0;
  x0 += x1; x1 = rotl_d(x1, 6);  x1 ^= x0;
  x0 += k1; x1 += ks2 + 1u;
  x0 += x1; x1 = rotl_d(x1, 17); x1 ^= x0;
  x0 += x1; x1 = rotl_d(x1, 29); x1 ^= x0;
  x0 += x1; x1 = rotl_d(x1, 16); x1 ^= x0;
  x0 += x1; x1 = rotl_d(x1, 24); x1 ^= x0;
  x0 += ks2; x1 += k0 + 2u;
  x0 += x1; x1 = rotl_d(x1, 13); x1 ^= x0;
  x0 += x1; x1 = rotl_d(x1, 15); x1 ^= x0;
  x0 += x1; x1 = rotl_d(x1, 26); x1 ^= x0;
  x0 += x1; x1 = rotl_d(x1, 6);  x1 ^= x0;
  x0 += k0; x1 += k1 + 3u;
  x0 += x1; x1 = rotl_d(x1, 17); x1 ^= x0;
  x0 += x1; x1 = rotl_d(x1, 29); x1 ^= x0;
  x0 += x1; x1 = rotl_d(x1, 16); x1 ^= x0;
  x0 += x1; x1 = rotl_d(x1, 24); x1 ^= x0;
  x0 += k1; x1 += ks2 + 4u;
  x0 += x1; x1 = rotl_d(x1, 13); x1 ^= x0;
  x0 += x1; x1 = rotl_d(x1, 15); x1 ^= x0;
  x0 += x1; x1 = rotl_d(x1, 26); x1 ^= x0;
  x0 += x1; x1 = rotl_d(x1, 6);  x1 ^= x0;
  x0 += ks2; x1 += k0 + 5u;
  return x0 ^ x1; // partitionable fold
}

__device__ __forceinline__ float bits_to_unit_float(uint32_t bits) {
  uint32_t fb = (bits >> 9) | 0x3f800000u;
  return __uint_as_float(fb) - 1.0f;
}

// ---------- precompute x_times (1024) and y_times (16384) ----------
__global__ void precompute_times(const int* __restrict__ in_sp,
                                 const int* __restrict__ out_sp,
                                 int* __restrict__ xt, int* __restrict__ yt) {
  int tid = blockIdx.x * 256 + threadIdx.x;
  if (tid < Y_SIZE) {
    int s = 0;
#pragma unroll
    for (int t = 0; t < 7; ++t) s += out_sp[t * Y_SIZE + tid];
    yt[tid] = 7 - s;
  } else if (tid < Y_SIZE + X_SIZE) {
    int j = tid - Y_SIZE;
    int s = 0;
#pragma unroll
    for (int t = 0; t < 7; ++t) s += in_sp[t * X_SIZE + j];
    xt[j] = 7 - s;
  }
}

// ---------- main kernel: one element per thread ----------
__global__ __launch_bounds__(256) void modstdp_part(const float* __restrict__ w,
                                                    const int* __restrict__ xt,
                                                    const int* __restrict__ yt,
                                                    float* __restrict__ out) {
  uint32_t i = blockIdx.x * 256u + threadIdx.x;
  float wv = w[i];
  int bx = xt[i & 1023u];
  uint32_t cout = (i >> 10) & 63u;
  uint32_t c = (i >> 16) & 15u;
  uint32_t r = i >> 20;
  int by = yt[cout * 256u + r * 16u + c];
  bool A = (bx == 7), B = (by == 7), Cg = (bx > by);
  float pp = (!A && B) ? 0.032f : ((!A && !B && !Cg) ? 0.102f : 0.0f);
  float pm = (A && !B) ? 0.96f : ((!A && !B && Cg) ? 0.051f : 0.0f);

  float u1 = bits_to_unit_float(threefry_fold_d(SK1.a, SK1.b, i));
  float u2 = bits_to_unit_float(threefry_fold_d(SK2.a, SK2.b, i));
  float u3 = bits_to_unit_float(threefry_fold_d(SK3.a, SK3.b, i));
  float u4 = bits_to_unit_float(threefry_fold_d(SK4.a, SK4.b, i));
  float u5 = bits_to_unit_float(threefry_fold_d(SK5.a, SK5.b, i));

  const float inv7 = (float)(1.0 / 7.0);
  float ratio = __fmul_rn(wv, inv7);
  float pFm = __fmul_rn(__fsub_rn(1.0f, ratio), __fadd_rn(1.0f, ratio));
  float pFp = __fmul_rn(ratio, __fsub_rn(2.0f, ratio));
  bool bp = u1 < pp;
  bool bm = u2 < pm;
  bool Fm = u3 < pFm;
  bool Fp = u4 < pFp;
  bool um = u5 < 0.008f;
  // fuse: delta = [bp && (Fp||um)] - [bm && (Fm||um)]  (mask ops -> SALU)
  bool inc = bp && (Fp || um);
  bool dec = bm && (Fm || um);
  float nw = wv + (inc ? 1.0f : 0.0f) - (dec ? 1.0f : 0.0f);
  out[i] = __builtin_amdgcn_fmed3f(nw, 0.0f, 7.0f); // single-instr clamp
}

extern "C" void kernel_launch(void* const* d_in, const int* in_sizes, int n_in,
                              void* d_out, int out_size, void* d_ws, size_t ws_size,
                              hipStream_t stream) {
  const float* w = (const float*)d_in[0];
  const int* isp = (const int*)d_in[1];
  const int* osp = (const int*)d_in[2];
  float* out = (float*)d_out;
  int* xt = (int*)d_ws;            // 1024 ints
  int* yt = ((int*)d_ws) + X_SIZE; // 16384 ints

  precompute_times<<<(Y_SIZE + X_SIZE + 255) / 256, 256, 0, stream>>>(isp, osp, xt, yt);
  modstdp_part<<<N_TOTAL / 256, 256, 0, stream>>>(w, xt, yt, out);
}

// Round 4
// 106.841 us; speedup vs baseline: 1.4075x; 1.3937x over previous
//
#include <hip/hip_runtime.h>
#include <stdint.h>

// JAX reproduction (verified bit-exact in R2, absmax 0.0):
//   jax_threefry_partitionable=True semantics:
//   split:  subkey[j] = threefry(key, hi=0, lo=j)  (foldlike, full pair)
//   bits:   bits[i]   = o0 ^ o1 of threefry(subkey, hi=0, lo=i)
// R4 change: bern_plus/bern_minus conditions are disjoint, and F_plus/F_minus
// are gated by bp/bm which are disjoint -> merge (u1,u2) and (u3,u4) into one
// per-lane-keyed threefry each: 5 -> 3 threefry per element.

#define N_TOTAL 16777216
#define Y_SIZE 16384 // COUT*R*C
#define X_SIZE 1024  // CIN*KH*KW

struct U2 { uint32_t a, b; };

// ---------- constexpr threefry (compile-time key derivation) ----------
constexpr uint32_t rotl_c(uint32_t x, int r) {
  return (x << r) | (x >> (32 - r));
}

constexpr U2 threefry_c(uint32_t k0, uint32_t k1, uint32_t x0, uint32_t x1) {
  uint32_t ks2 = k0 ^ k1 ^ 0x1BD11BDAu;
  x0 += k0; x1 += k1;
  x0 += x1; x1 = rotl_c(x1, 13); x1 ^= x0;
  x0 += x1; x1 = rotl_c(x1, 15); x1 ^= x0;
  x0 += x1; x1 = rotl_c(x1, 26); x1 ^= x0;
  x0 += x1; x1 = rotl_c(x1, 6);  x1 ^= x0;
  x0 += k1; x1 += ks2 + 1u;
  x0 += x1; x1 = rotl_c(x1, 17); x1 ^= x0;
  x0 += x1; x1 = rotl_c(x1, 29); x1 ^= x0;
  x0 += x1; x1 = rotl_c(x1, 16); x1 ^= x0;
  x0 += x1; x1 = rotl_c(x1, 24); x1 ^= x0;
  x0 += ks2; x1 += k0 + 2u;
  x0 += x1; x1 = rotl_c(x1, 13); x1 ^= x0;
  x0 += x1; x1 = rotl_c(x1, 15); x1 ^= x0;
  x0 += x1; x1 = rotl_c(x1, 26); x1 ^= x0;
  x0 += x1; x1 = rotl_c(x1, 6);  x1 ^= x0;
  x0 += k0; x1 += k1 + 3u;
  x0 += x1; x1 = rotl_c(x1, 17); x1 ^= x0;
  x0 += x1; x1 = rotl_c(x1, 29); x1 ^= x0;
  x0 += x1; x1 = rotl_c(x1, 16); x1 ^= x0;
  x0 += x1; x1 = rotl_c(x1, 24); x1 ^= x0;
  x0 += k1; x1 += ks2 + 4u;
  x0 += x1; x1 = rotl_c(x1, 13); x1 ^= x0;
  x0 += x1; x1 = rotl_c(x1, 15); x1 ^= x0;
  x0 += x1; x1 = rotl_c(x1, 26); x1 ^= x0;
  x0 += x1; x1 = rotl_c(x1, 6);  x1 ^= x0;
  x0 += ks2; x1 += k0 + 5u;
  return {x0, x1};
}

// foldlike split of key(42)
constexpr U2 SK1 = threefry_c(0u, 42u, 0u, 0u); // bern_plus
constexpr U2 SK2 = threefry_c(0u, 42u, 0u, 1u); // bern_minus
constexpr U2 SK3 = threefry_c(0u, 42u, 0u, 2u); // F_minus_raw
constexpr U2 SK4 = threefry_c(0u, 42u, 0u, 3u); // F_plus_raw
constexpr U2 SK5 = threefry_c(0u, 42u, 0u, 4u); // umin

// Integer Bernoulli threshold: u < p  <=>  bits < (ceil(p*2^23) << 9),
// exact because u = (bits>>9) * 2^-23 exactly and p*2^23 is exact in double.
constexpr uint32_t bern_thr(float pf) {
  double p8 = (double)pf * 8388608.0;
  uint64_t t = (uint64_t)p8;
  if ((double)t < p8) t += 1u; // ceil
  return (uint32_t)(t << 9);
}
constexpr uint32_t T_SEARCH  = bern_thr(0.032f);
constexpr uint32_t T_CAPTURE = bern_thr(0.102f);
constexpr uint32_t T_BACKOFF = bern_thr(0.96f);
constexpr uint32_t T_MINUS   = bern_thr(0.051f);
constexpr uint32_t T_UMIN    = bern_thr(0.008f);

// ---------- device threefry fold (works with SGPR or VGPR keys) ----------
__device__ __forceinline__ uint32_t rotl_d(uint32_t x, int r) {
  return __builtin_amdgcn_alignbit(x, x, 32 - r);
}

__device__ __forceinline__ uint32_t tf_fold(uint32_t k0, uint32_t k1,
                                            uint32_t ctr) {
  uint32_t ks2 = k0 ^ k1 ^ 0x1BD11BDAu;
  uint32_t x0 = k0;        // 0 + k0
  uint32_t x1 = ctr + k1;
  x0 += x1; x1 = rotl_d(x1, 13); x1 ^= x0;
  x0 += x1; x1 = rotl_d(x1, 15); x1 ^= x0;
  x0 += x1; x1 = rotl_d(x1, 26); x1 ^= x0;
  x0 += x1; x1 = rotl_d(x1, 6);  x1 ^= x0;
  x0 += k1; x1 += ks2 + 1u;
  x0 += x1; x1 = rotl_d(x1, 17); x1 ^= x0;
  x0 += x1; x1 = rotl_d(x1, 29); x1 ^= x0;
  x0 += x1; x1 = rotl_d(x1, 16); x1 ^= x0;
  x0 += x1; x1 = rotl_d(x1, 24); x1 ^= x0;
  x0 += ks2; x1 += k0 + 2u;
  x0 += x1; x1 = rotl_d(x1, 13); x1 ^= x0;
  x0 += x1; x1 = rotl_d(x1, 15); x1 ^= x0;
  x0 += x1; x1 = rotl_d(x1, 26); x1 ^= x0;
  x0 += x1; x1 = rotl_d(x1, 6);  x1 ^= x0;
  x0 += k0; x1 += k1 + 3u;
  x0 += x1; x1 = rotl_d(x1, 17); x1 ^= x0;
  x0 += x1; x1 = rotl_d(x1, 29); x1 ^= x0;
  x0 += x1; x1 = rotl_d(x1, 16); x1 ^= x0;
  x0 += x1; x1 = rotl_d(x1, 24); x1 ^= x0;
  x0 += k1; x1 += ks2 + 4u;
  x0 += x1; x1 = rotl_d(x1, 13); x1 ^= x0;
  x0 += x1; x1 = rotl_d(x1, 15); x1 ^= x0;
  x0 += x1; x1 = rotl_d(x1, 26); x1 ^= x0;
  x0 += x1; x1 = rotl_d(x1, 6);  x1 ^= x0;
  x0 += ks2; x1 += k0 + 5u;
  return x0 ^ x1; // partitionable fold
}

__device__ __forceinline__ float bits_to_unit_float(uint32_t bits) {
  uint32_t fb = (bits >> 9) | 0x3f800000u;
  return __uint_as_float(fb) - 1.0f;
}

// ---------- precompute x_times (1024) and y_times (16384) ----------
__global__ void precompute_times(const int* __restrict__ in_sp,
                                 const int* __restrict__ out_sp,
                                 int* __restrict__ xt, int* __restrict__ yt) {
  int tid = blockIdx.x * 256 + threadIdx.x;
  if (tid < Y_SIZE) {
    int s = 0;
#pragma unroll
    for (int t = 0; t < 7; ++t) s += out_sp[t * Y_SIZE + tid];
    yt[tid] = 7 - s;
  } else if (tid < Y_SIZE + X_SIZE) {
    int j = tid - Y_SIZE;
    int s = 0;
#pragma unroll
    for (int t = 0; t < 7; ++t) s += in_sp[t * X_SIZE + j];
    xt[j] = 7 - s;
  }
}

// ---------- main kernel: 4 elements per thread, 3 threefry per element ----------
__global__ __launch_bounds__(256) void modstdp4(const float* __restrict__ w,
                                                const int* __restrict__ xt,
                                                const int* __restrict__ yt,
                                                float* __restrict__ out) {
  uint32_t t = blockIdx.x * 256u + threadIdx.x;
  uint32_t i0 = t * 4u;

  float4 wv = *reinterpret_cast<const float4*>(w + i0);
  int4 bxv = *reinterpret_cast<const int4*>(xt + (i0 & 1023u));
  float warr[4]; *reinterpret_cast<float4*>(warr) = wv;
  int barr[4];   *reinterpret_cast<int4*>(barr) = bxv;

  // 4 consecutive elements share cout,r,c -> one yt lookup
  uint32_t cout = (i0 >> 10) & 63u;
  uint32_t c = (i0 >> 16) & 15u;
  uint32_t r = i0 >> 20;
  int by = yt[cout * 256u + r * 16u + c];
  bool B = (by == 7);

  float res[4];
#pragma unroll
  for (int e = 0; e < 4; ++e) {
    uint32_t i = i0 + (uint32_t)e;
    int bx = barr[e];
    float wf = warr[e];
    bool A = (bx == 7), Cg = (bx > by);

    // thr12 / selM per the reference's disjoint where-nesting:
    //  pp: (!A&&B)->SEARCH, (!A&&!B&&!Cg)->CAPTURE, else 0
    //  pm: (A&&!B)->BACKOFF, (!A&&!B&&Cg)->MINUS,   else 0
    uint32_t thr12 = A ? (B ? 0u : T_BACKOFF)
                       : (B ? T_SEARCH : (Cg ? T_MINUS : T_CAPTURE));
    bool selM = A ? !B : (!B && Cg); // minus-branch active (pm>0)

    uint32_t k12a = selM ? SK2.a : SK1.a;
    uint32_t k12b = selM ? SK2.b : SK1.b;
    uint32_t bits12 = tf_fold(k12a, k12b, i);
    bool hit = bits12 < thr12; // == (selM ? bm : bp)
    bool bm = hit && selM;

    // F-stream: key SK3 for bm-lanes, SK4 for bp-lanes (never both needed)
    uint32_t k34a = bm ? SK3.a : SK4.a;
    uint32_t k34b = bm ? SK3.b : SK4.b;
    uint32_t bits34 = tf_fold(k34a, k34b, i);
    uint32_t bits5 = tf_fold(SK5.a, SK5.b, i);

    const float inv7 = (float)(1.0 / 7.0);
    float ratio = __fmul_rn(wf, inv7);
    float pFm = __fmul_rn(__fsub_rn(1.0f, ratio), __fadd_rn(1.0f, ratio));
    float pFp = __fmul_rn(ratio, __fsub_rn(2.0f, ratio));
    float thrF = bm ? pFm : pFp;
    bool F = bits_to_unit_float(bits34) < thrF;
    bool um = bits5 < T_UMIN;

    bool go = hit && (F || um); // == bp&&(Fp||um)  or  bm&&(Fm||um)
    float delta = go ? (selM ? -1.0f : 1.0f) : 0.0f;
    res[e] = __builtin_amdgcn_fmed3f(wf + delta, 0.0f, 7.0f);
  }

  *reinterpret_cast<float4*>(out + i0) =
      make_float4(res[0], res[1], res[2], res[3]);
}

extern "C" void kernel_launch(void* const* d_in, const int* in_sizes, int n_in,
                              void* d_out, int out_size, void* d_ws, size_t ws_size,
                              hipStream_t stream) {
  const float* w = (const float*)d_in[0];
  const int* isp = (const int*)d_in[1];
  const int* osp = (const int*)d_in[2];
  float* out = (float*)d_out;
  int* xt = (int*)d_ws;            // 1024 ints
  int* yt = ((int*)d_ws) + X_SIZE; // 16384 ints

  precompute_times<<<(Y_SIZE + X_SIZE + 255) / 256, 256, 0, stream>>>(isp, osp, xt, yt);
  modstdp4<<<N_TOTAL / 4 / 256, 256, 0, stream>>>(w, xt, yt, out);
}

// Round 5
// 67.347 us; speedup vs baseline: 2.2329x; 1.5864x over previous
//
#include <hip/hip_runtime.h>
#include <stdint.h>

// JAX reproduction (verified bit-exact R2/R4):
//   partitionable split: subkey[j] = threefry(key,0,j); bits[i] = fold o0^o1.
// R4: disjointness merged 5 streams -> 3 threefry/element.
// R5: intra-wave compaction — bits34/bits5 only computed for 'hit' items
//     (P~0.09), remapped onto lanes 0..cnt-1 via ballot/mbcnt + LDS routing.

#define N_TOTAL 16777216
#define Y_SIZE 16384 // COUT*R*C
#define X_SIZE 1024  // CIN*KH*KW

struct U2 { uint32_t a, b; };

// ---------- constexpr threefry (compile-time key derivation) ----------
constexpr uint32_t rotl_c(uint32_t x, int r) {
  return (x << r) | (x >> (32 - r));
}

constexpr U2 threefry_c(uint32_t k0, uint32_t k1, uint32_t x0, uint32_t x1) {
  uint32_t ks2 = k0 ^ k1 ^ 0x1BD11BDAu;
  x0 += k0; x1 += k1;
  x0 += x1; x1 = rotl_c(x1, 13); x1 ^= x0;
  x0 += x1; x1 = rotl_c(x1, 15); x1 ^= x0;
  x0 += x1; x1 = rotl_c(x1, 26); x1 ^= x0;
  x0 += x1; x1 = rotl_c(x1, 6);  x1 ^= x0;
  x0 += k1; x1 += ks2 + 1u;
  x0 += x1; x1 = rotl_c(x1, 17); x1 ^= x0;
  x0 += x1; x1 = rotl_c(x1, 29); x1 ^= x0;
  x0 += x1; x1 = rotl_c(x1, 16); x1 ^= x0;
  x0 += x1; x1 = rotl_c(x1, 24); x1 ^= x0;
  x0 += ks2; x1 += k0 + 2u;
  x0 += x1; x1 = rotl_c(x1, 13); x1 ^= x0;
  x0 += x1; x1 = rotl_c(x1, 15); x1 ^= x0;
  x0 += x1; x1 = rotl_c(x1, 26); x1 ^= x0;
  x0 += x1; x1 = rotl_c(x1, 6);  x1 ^= x0;
  x0 += k0; x1 += k1 + 3u;
  x0 += x1; x1 = rotl_c(x1, 17); x1 ^= x0;
  x0 += x1; x1 = rotl_c(x1, 29); x1 ^= x0;
  x0 += x1; x1 = rotl_c(x1, 16); x1 ^= x0;
  x0 += x1; x1 = rotl_c(x1, 24); x1 ^= x0;
  x0 += k1; x1 += ks2 + 4u;
  x0 += x1; x1 = rotl_c(x1, 13); x1 ^= x0;
  x0 += x1; x1 = rotl_c(x1, 15); x1 ^= x0;
  x0 += x1; x1 = rotl_c(x1, 26); x1 ^= x0;
  x0 += x1; x1 = rotl_c(x1, 6);  x1 ^= x0;
  x0 += ks2; x1 += k0 + 5u;
  return {x0, x1};
}

constexpr U2 SK1 = threefry_c(0u, 42u, 0u, 0u); // bern_plus
constexpr U2 SK2 = threefry_c(0u, 42u, 0u, 1u); // bern_minus
constexpr U2 SK3 = threefry_c(0u, 42u, 0u, 2u); // F_minus_raw
constexpr U2 SK4 = threefry_c(0u, 42u, 0u, 3u); // F_plus_raw
constexpr U2 SK5 = threefry_c(0u, 42u, 0u, 4u); // umin

// u < p  <=>  bits < (ceil(p*2^23) << 9)   (exact)
constexpr uint32_t bern_thr(float pf) {
  double p8 = (double)pf * 8388608.0;
  uint64_t t = (uint64_t)p8;
  if ((double)t < p8) t += 1u;
  return (uint32_t)(t << 9);
}
constexpr uint32_t T_SEARCH  = bern_thr(0.032f);
constexpr uint32_t T_CAPTURE = bern_thr(0.102f);
constexpr uint32_t T_BACKOFF = bern_thr(0.96f);
constexpr uint32_t T_MINUS   = bern_thr(0.051f);
constexpr uint32_t T_UMIN    = bern_thr(0.008f);

__device__ __forceinline__ uint32_t rotl_d(uint32_t x, int r) {
  return __builtin_amdgcn_alignbit(x, x, 32 - r);
}

__device__ __forceinline__ uint32_t tf_fold(uint32_t k0, uint32_t k1,
                                            uint32_t ctr) {
  uint32_t ks2 = k0 ^ k1 ^ 0x1BD11BDAu;
  uint32_t x0 = k0;        // 0 + k0
  uint32_t x1 = ctr + k1;
  x0 += x1; x1 = rotl_d(x1, 13); x1 ^= x0;
  x0 += x1; x1 = rotl_d(x1, 15); x1 ^= x0;
  x0 += x1; x1 = rotl_d(x1, 26); x1 ^= x0;
  x0 += x1; x1 = rotl_d(x1, 6);  x1 ^= x0;
  x0 += k1; x1 += ks2 + 1u;
  x0 += x1; x1 = rotl_d(x1, 17); x1 ^= x0;
  x0 += x1; x1 = rotl_d(x1, 29); x1 ^= x0;
  x0 += x1; x1 = rotl_d(x1, 16); x1 ^= x0;
  x0 += x1; x1 = rotl_d(x1, 24); x1 ^= x0;
  x0 += ks2; x1 += k0 + 2u;
  x0 += x1; x1 = rotl_d(x1, 13); x1 ^= x0;
  x0 += x1; x1 = rotl_d(x1, 15); x1 ^= x0;
  x0 += x1; x1 = rotl_d(x1, 26); x1 ^= x0;
  x0 += x1; x1 = rotl_d(x1, 6);  x1 ^= x0;
  x0 += k0; x1 += k1 + 3u;
  x0 += x1; x1 = rotl_d(x1, 17); x1 ^= x0;
  x0 += x1; x1 = rotl_d(x1, 29); x1 ^= x0;
  x0 += x1; x1 = rotl_d(x1, 16); x1 ^= x0;
  x0 += x1; x1 = rotl_d(x1, 24); x1 ^= x0;
  x0 += k1; x1 += ks2 + 4u;
  x0 += x1; x1 = rotl_d(x1, 13); x1 ^= x0;
  x0 += x1; x1 = rotl_d(x1, 15); x1 ^= x0;
  x0 += x1; x1 = rotl_d(x1, 26); x1 ^= x0;
  x0 += x1; x1 = rotl_d(x1, 6);  x1 ^= x0;
  x0 += ks2; x1 += k0 + 5u;
  return x0 ^ x1;
}

__device__ __forceinline__ float bits_to_unit_float(uint32_t bits) {
  uint32_t fb = (bits >> 9) | 0x3f800000u;
  return __uint_as_float(fb) - 1.0f;
}

__device__ __forceinline__ uint32_t mbcnt64(uint64_t m) {
  return __builtin_amdgcn_mbcnt_hi((uint32_t)(m >> 32),
         __builtin_amdgcn_mbcnt_lo((uint32_t)m, 0u));
}

// ---------- precompute x_times (1024) and y_times (16384) ----------
__global__ void precompute_times(const int* __restrict__ in_sp,
                                 const int* __restrict__ out_sp,
                                 int* __restrict__ xt, int* __restrict__ yt) {
  int tid = blockIdx.x * 256 + threadIdx.x;
  if (tid < Y_SIZE) {
    int s = 0;
#pragma unroll
    for (int t = 0; t < 7; ++t) s += out_sp[t * Y_SIZE + tid];
    yt[tid] = 7 - s;
  } else if (tid < Y_SIZE + X_SIZE) {
    int j = tid - Y_SIZE;
    int s = 0;
#pragma unroll
    for (int t = 0; t < 7; ++t) s += in_sp[t * X_SIZE + j];
    xt[j] = 7 - s;
  }
}

// ---------- main kernel: 4 elem/thread; conditional streams compacted ----------
__global__ __launch_bounds__(256) void modstdp4c(const float* __restrict__ w,
                                                 const int* __restrict__ xt,
                                                 const int* __restrict__ yt,
                                                 float* __restrict__ out) {
  __shared__ uint2 rec[1024];    // per-wave 256-slot slices: (ctr|selM<<31, thrF)
  __shared__ uint32_t okb[1024]; // helper results

  uint32_t tid = threadIdx.x;
  uint32_t lane = tid & 63u;
  uint32_t wbase = (tid >> 6) * 256u;
  uint32_t t = blockIdx.x * 256u + tid;
  uint32_t i0 = t * 4u;

  float4 wv = *reinterpret_cast<const float4*>(w + i0);
  int4 bxv = *reinterpret_cast<const int4*>(xt + (i0 & 1023u));
  float warr[4]; *reinterpret_cast<float4*>(warr) = wv;
  int barr[4];   *reinterpret_cast<int4*>(barr) = bxv;

  // 4 consecutive elements share cout,r,c -> one yt lookup
  uint32_t cout = (i0 >> 10) & 63u;
  uint32_t c = (i0 >> 16) & 15u;
  uint32_t r = i0 >> 20;
  int by = yt[cout * 256u + r * 16u + c];
  bool B = (by == 7);

  bool hit[4], sM[4];
  uint32_t rank[4];
  uint32_t cnt = 0;

#pragma unroll
  for (int e = 0; e < 4; ++e) {
    uint32_t i = i0 + (uint32_t)e;
    int bx = barr[e];
    float wf = warr[e];
    bool A = (bx == 7), Cg = (bx > by);

    uint32_t thr12 = A ? (B ? 0u : T_BACKOFF)
                       : (B ? T_SEARCH : (Cg ? T_MINUS : T_CAPTURE));
    bool selM = A ? !B : (!B && Cg); // minus-branch active
    sM[e] = selM;

    uint32_t k12a = selM ? SK2.a : SK1.a;
    uint32_t k12b = selM ? SK2.b : SK1.b;
    uint32_t bits12 = tf_fold(k12a, k12b, i);
    bool h = bits12 < thr12;
    hit[e] = h;

    // F-threshold (exact reference float ops), needed only if hit
    const float inv7 = (float)(1.0 / 7.0);
    float ratio = __fmul_rn(wf, inv7);
    float pFm = __fmul_rn(__fsub_rn(1.0f, ratio), __fadd_rn(1.0f, ratio));
    float pFp = __fmul_rn(ratio, __fsub_rn(2.0f, ratio));
    float thrF = selM ? pFm : pFp;

    uint64_t m = __ballot(h);
    uint32_t rk = cnt + mbcnt64(m);
    rank[e] = rk;
    cnt += (uint32_t)__popcll(m);
    if (h) {
      rec[wbase + rk] = make_uint2(i | ((uint32_t)selM << 31),
                                   __float_as_uint(thrF));
    }
  }

  // helpers: lanes 0..cnt-1 handle one hit item each (loop ~always 1 iter)
  for (uint32_t base = 0; base < cnt; base += 64u) {
    uint32_t idx = base + lane;
    if (idx < cnt) {
      uint2 rc = rec[wbase + idx];
      bool selM = (rc.x >> 31) != 0u;
      uint32_t ctr = rc.x & 0x7fffffffu;
      uint32_t k34a = selM ? SK3.a : SK4.a; // bm==selM for hit items
      uint32_t k34b = selM ? SK3.b : SK4.b;
      uint32_t bits34 = tf_fold(k34a, k34b, ctr);
      uint32_t bits5 = tf_fold(SK5.a, SK5.b, ctr);
      bool ok = (bits_to_unit_float(bits34) < __uint_as_float(rc.y)) |
                (bits5 < T_UMIN);
      okb[wbase + idx] = ok ? 1u : 0u;
    }
  }

  // readback + finalize
  float res[4];
#pragma unroll
  for (int e = 0; e < 4; ++e) {
    float d = 0.0f;
    if (hit[e]) {
      uint32_t ok = okb[wbase + rank[e]];
      d = ok ? (sM[e] ? -1.0f : 1.0f) : 0.0f;
    }
    res[e] = __builtin_amdgcn_fmed3f(warr[e] + d, 0.0f, 7.0f);
  }
  *reinterpret_cast<float4*>(out + i0) =
      make_float4(res[0], res[1], res[2], res[3]);
}

extern "C" void kernel_launch(void* const* d_in, const int* in_sizes, int n_in,
                              void* d_out, int out_size, void* d_ws, size_t ws_size,
                              hipStream_t stream) {
  const float* w = (const float*)d_in[0];
  const int* isp = (const int*)d_in[1];
  const int* osp = (const int*)d_in[2];
  float* out = (float*)d_out;
  int* xt = (int*)d_ws;            // 1024 ints
  int* yt = ((int*)d_ws) + X_SIZE; // 16384 ints

  precompute_times<<<(Y_SIZE + X_SIZE + 255) / 256, 256, 0, stream>>>(isp, osp, xt, yt);
  modstdp4c<<<N_TOTAL / 4 / 256, 256, 0, stream>>>(w, xt, yt, out);
}

// Round 6
// 64.346 us; speedup vs baseline: 2.3371x; 1.0466x over previous
//
#include <hip/hip_runtime.h>
#include <stdint.h>

// JAX reproduction (verified bit-exact R2/R4/R5):
//   partitionable split: subkey[j] = threefry(key,0,j); bits[i] = fold o0^o1.
// R4: disjointness merged 5 streams -> 3 threefry/element.
// R5: intra-wave compaction: streams 34/5 only for 'hit' items (P~0.09).
// R6: 64-entry LDS table for (thr12|selM, k12a, k12b, ks2) keyed by (bx,by);
//     thrF computation moved to helper stage (rec stores weight bits).

#define N_TOTAL 16777216
#define Y_SIZE 16384 // COUT*R*C
#define X_SIZE 1024  // CIN*KH*KW

struct U2 { uint32_t a, b; };

// ---------- constexpr threefry (compile-time key derivation) ----------
constexpr uint32_t rotl_c(uint32_t x, int r) {
  return (x << r) | (x >> (32 - r));
}

constexpr U2 threefry_c(uint32_t k0, uint32_t k1, uint32_t x0, uint32_t x1) {
  uint32_t ks2 = k0 ^ k1 ^ 0x1BD11BDAu;
  x0 += k0; x1 += k1;
  x0 += x1; x1 = rotl_c(x1, 13); x1 ^= x0;
  x0 += x1; x1 = rotl_c(x1, 15); x1 ^= x0;
  x0 += x1; x1 = rotl_c(x1, 26); x1 ^= x0;
  x0 += x1; x1 = rotl_c(x1, 6);  x1 ^= x0;
  x0 += k1; x1 += ks2 + 1u;
  x0 += x1; x1 = rotl_c(x1, 17); x1 ^= x0;
  x0 += x1; x1 = rotl_c(x1, 29); x1 ^= x0;
  x0 += x1; x1 = rotl_c(x1, 16); x1 ^= x0;
  x0 += x1; x1 = rotl_c(x1, 24); x1 ^= x0;
  x0 += ks2; x1 += k0 + 2u;
  x0 += x1; x1 = rotl_c(x1, 13); x1 ^= x0;
  x0 += x1; x1 = rotl_c(x1, 15); x1 ^= x0;
  x0 += x1; x1 = rotl_c(x1, 26); x1 ^= x0;
  x0 += x1; x1 = rotl_c(x1, 6);  x1 ^= x0;
  x0 += k0; x1 += k1 + 3u;
  x0 += x1; x1 = rotl_c(x1, 17); x1 ^= x0;
  x0 += x1; x1 = rotl_c(x1, 29); x1 ^= x0;
  x0 += x1; x1 = rotl_c(x1, 16); x1 ^= x0;
  x0 += x1; x1 = rotl_c(x1, 24); x1 ^= x0;
  x0 += k1; x1 += ks2 + 4u;
  x0 += x1; x1 = rotl_c(x1, 13); x1 ^= x0;
  x0 += x1; x1 = rotl_c(x1, 15); x1 ^= x0;
  x0 += x1; x1 = rotl_c(x1, 26); x1 ^= x0;
  x0 += x1; x1 = rotl_c(x1, 6);  x1 ^= x0;
  x0 += ks2; x1 += k0 + 5u;
  return {x0, x1};
}

constexpr U2 SK1 = threefry_c(0u, 42u, 0u, 0u); // bern_plus
constexpr U2 SK2 = threefry_c(0u, 42u, 0u, 1u); // bern_minus
constexpr U2 SK3 = threefry_c(0u, 42u, 0u, 2u); // F_minus_raw
constexpr U2 SK4 = threefry_c(0u, 42u, 0u, 3u); // F_plus_raw
constexpr U2 SK5 = threefry_c(0u, 42u, 0u, 4u); // umin

constexpr uint32_t KS2_3 = SK3.a ^ SK3.b ^ 0x1BD11BDAu;
constexpr uint32_t KS2_4 = SK4.a ^ SK4.b ^ 0x1BD11BDAu;
constexpr uint32_t KS2_5 = SK5.a ^ SK5.b ^ 0x1BD11BDAu;

// u < p  <=>  bits < (ceil(p*2^23) << 9)   (exact)
constexpr uint32_t bern_thr(float pf) {
  double p8 = (double)pf * 8388608.0;
  uint64_t t = (uint64_t)p8;
  if ((double)t < p8) t += 1u;
  return (uint32_t)(t << 9);
}
constexpr uint32_t T_SEARCH  = bern_thr(0.032f);
constexpr uint32_t T_CAPTURE = bern_thr(0.102f);
constexpr uint32_t T_BACKOFF = bern_thr(0.96f);
constexpr uint32_t T_MINUS   = bern_thr(0.051f);
constexpr uint32_t T_UMIN    = bern_thr(0.008f);

__device__ __forceinline__ uint32_t rotl_d(uint32_t x, int r) {
  return __builtin_amdgcn_alignbit(x, x, 32 - r);
}

// threefry fold with precomputed ks2 (keys may be VGPR or SGPR)
__device__ __forceinline__ uint32_t tf_fold_k(uint32_t k0, uint32_t k1,
                                              uint32_t ks2, uint32_t ctr) {
  uint32_t x0 = k0;        // 0 + k0
  uint32_t x1 = ctr + k1;
  x0 += x1; x1 = rotl_d(x1, 13); x1 ^= x0;
  x0 += x1; x1 = rotl_d(x1, 15); x1 ^= x0;
  x0 += x1; x1 = rotl_d(x1, 26); x1 ^= x0;
  x0 += x1; x1 = rotl_d(x1, 6);  x1 ^= x0;
  x0 += k1; x1 += ks2 + 1u;
  x0 += x1; x1 = rotl_d(x1, 17); x1 ^= x0;
  x0 += x1; x1 = rotl_d(x1, 29); x1 ^= x0;
  x0 += x1; x1 = rotl_d(x1, 16); x1 ^= x0;
  x0 += x1; x1 = rotl_d(x1, 24); x1 ^= x0;
  x0 += ks2; x1 += k0 + 2u;
  x0 += x1; x1 = rotl_d(x1, 13); x1 ^= x0;
  x0 += x1; x1 = rotl_d(x1, 15); x1 ^= x0;
  x0 += x1; x1 = rotl_d(x1, 26); x1 ^= x0;
  x0 += x1; x1 = rotl_d(x1, 6);  x1 ^= x0;
  x0 += k0; x1 += k1 + 3u;
  x0 += x1; x1 = rotl_d(x1, 17); x1 ^= x0;
  x0 += x1; x1 = rotl_d(x1, 29); x1 ^= x0;
  x0 += x1; x1 = rotl_d(x1, 16); x1 ^= x0;
  x0 += x1; x1 = rotl_d(x1, 24); x1 ^= x0;
  x0 += k1; x1 += ks2 + 4u;
  x0 += x1; x1 = rotl_d(x1, 13); x1 ^= x0;
  x0 += x1; x1 = rotl_d(x1, 15); x1 ^= x0;
  x0 += x1; x1 = rotl_d(x1, 26); x1 ^= x0;
  x0 += x1; x1 = rotl_d(x1, 6);  x1 ^= x0;
  x0 += ks2; x1 += k0 + 5u;
  return x0 ^ x1;
}

__device__ __forceinline__ float bits_to_unit_float(uint32_t bits) {
  uint32_t fb = (bits >> 9) | 0x3f800000u;
  return __uint_as_float(fb) - 1.0f;
}

__device__ __forceinline__ uint32_t mbcnt64(uint64_t m) {
  return __builtin_amdgcn_mbcnt_hi((uint32_t)(m >> 32),
         __builtin_amdgcn_mbcnt_lo((uint32_t)m, 0u));
}

// ---------- precompute x_times (1024) and y_times (16384) ----------
__global__ void precompute_times(const int* __restrict__ in_sp,
                                 const int* __restrict__ out_sp,
                                 int* __restrict__ xt, int* __restrict__ yt) {
  int tid = blockIdx.x * 256 + threadIdx.x;
  if (tid < Y_SIZE) {
    int s = 0;
#pragma unroll
    for (int t = 0; t < 7; ++t) s += out_sp[t * Y_SIZE + tid];
    yt[tid] = 7 - s;
  } else if (tid < Y_SIZE + X_SIZE) {
    int j = tid - Y_SIZE;
    int s = 0;
#pragma unroll
    for (int t = 0; t < 7; ++t) s += in_sp[t * X_SIZE + j];
    xt[j] = 7 - s;
  }
}

// ---------- main kernel: 4 elem/thread; (bx,by)-table + compaction ----------
__global__ __launch_bounds__(256) void modstdp4t(const float* __restrict__ w,
                                                 const int* __restrict__ xt,
                                                 const int* __restrict__ yt,
                                                 float* __restrict__ out) {
  __shared__ uint4 tbl[64];      // (thr12|selM, k12a, k12b, ks2) by bx*8+by
  __shared__ uint2 rec[1024];    // per-wave 256-slot slices: (ctr|selM<<31, wbits)
  __shared__ uint32_t okb[1024]; // helper results

  uint32_t tid = threadIdx.x;

  if (tid < 64u) {
    uint32_t bx = tid >> 3, by = tid & 7u;
    bool A = (bx == 7u), B = (by == 7u), Cg = (bx > by);
    uint32_t thr = A ? (B ? 0u : T_BACKOFF)
                     : (B ? T_SEARCH : (Cg ? T_MINUS : T_CAPTURE));
    bool selM = A ? !B : (!B && Cg);
    uint32_t k0 = selM ? SK2.a : SK1.a;
    uint32_t k1 = selM ? SK2.b : SK1.b;
    tbl[tid] = make_uint4(thr | (uint32_t)selM, k0, k1,
                          k0 ^ k1 ^ 0x1BD11BDAu);
  }
  __syncthreads();

  uint32_t lane = tid & 63u;
  uint32_t wbase = (tid >> 6) * 256u;
  uint32_t t = blockIdx.x * 256u + tid;
  uint32_t i0 = t * 4u;

  float4 wv = *reinterpret_cast<const float4*>(w + i0);
  int4 bxv = *reinterpret_cast<const int4*>(xt + (i0 & 1023u));
  float warr[4]; *reinterpret_cast<float4*>(warr) = wv;
  int barr[4];   *reinterpret_cast<int4*>(barr) = bxv;

  // 4 consecutive elements share cout,r,c -> one yt lookup
  uint32_t cout = (i0 >> 10) & 63u;
  uint32_t c = (i0 >> 16) & 15u;
  uint32_t r = i0 >> 20;
  uint32_t by = (uint32_t)yt[cout * 256u + r * 16u + c];

  bool hit[4];
  uint32_t sMb[4];
  uint32_t rank[4];
  uint32_t cnt = 0;

#pragma unroll
  for (int e = 0; e < 4; ++e) {
    uint32_t i = i0 + (uint32_t)e;
    uint4 en = tbl[(uint32_t)barr[e] * 8u + by];
    uint32_t thr = en.x & 0xFFFFFE00u;
    uint32_t selMb = en.x & 1u;
    sMb[e] = selMb;

    uint32_t bits12 = tf_fold_k(en.y, en.z, en.w, i);
    bool h = bits12 < thr;
    hit[e] = h;

    uint64_t m = __ballot(h);
    cnt += (uint32_t)__popcll(m);
    if (h) {
      uint32_t rk = (cnt - (uint32_t)__popcll(m)) + mbcnt64(m);
      rank[e] = rk;
      rec[wbase + rk] = make_uint2(i | (selMb << 31),
                                   __float_as_uint(warr[e]));
    }
  }

  // helpers: lanes 0..cnt-1 handle one hit item each (~always one pass)
  for (uint32_t base = 0; base < cnt; base += 64u) {
    uint32_t idx = base + lane;
    if (idx < cnt) {
      uint2 rc = rec[wbase + idx];
      bool sm = (rc.x >> 31) != 0u;
      uint32_t ctr = rc.x & 0x7fffffffu;
      float wf = __uint_as_float(rc.y);

      const float inv7 = (float)(1.0 / 7.0);
      float ratio = __fmul_rn(wf, inv7);
      float thrF = sm
          ? __fmul_rn(__fsub_rn(1.0f, ratio), __fadd_rn(1.0f, ratio))  // pFm
          : __fmul_rn(ratio, __fsub_rn(2.0f, ratio));                  // pFp

      uint32_t k34a = sm ? SK3.a : SK4.a;
      uint32_t k34b = sm ? SK3.b : SK4.b;
      uint32_t ks34 = sm ? KS2_3 : KS2_4;
      uint32_t bits34 = tf_fold_k(k34a, k34b, ks34, ctr);
      uint32_t bits5 = tf_fold_k(SK5.a, SK5.b, KS2_5, ctr);
      bool ok = (bits_to_unit_float(bits34) < thrF) | (bits5 < T_UMIN);
      okb[wbase + idx] = ok ? 1u : 0u;
    }
  }

  // readback + finalize
  float res[4];
#pragma unroll
  for (int e = 0; e < 4; ++e) {
    float d = 0.0f;
    if (hit[e]) {
      uint32_t ok = okb[wbase + rank[e]];
      d = ok ? (sMb[e] ? -1.0f : 1.0f) : 0.0f;
    }
    res[e] = __builtin_amdgcn_fmed3f(warr[e] + d, 0.0f, 7.0f);
  }
  *reinterpret_cast<float4*>(out + i0) =
      make_float4(res[0], res[1], res[2], res[3]);
}

extern "C" void kernel_launch(void* const* d_in, const int* in_sizes, int n_in,
                              void* d_out, int out_size, void* d_ws, size_t ws_size,
                              hipStream_t stream) {
  const float* w = (const float*)d_in[0];
  const int* isp = (const int*)d_in[1];
  const int* osp = (const int*)d_in[2];
  float* out = (float*)d_out;
  int* xt = (int*)d_ws;            // 1024 ints
  int* yt = ((int*)d_ws) + X_SIZE; // 16384 ints

  precompute_times<<<(Y_SIZE + X_SIZE + 255) / 256, 256, 0, stream>>>(isp, osp, xt, yt);
  modstdp4t<<<N_TOTAL / 4 / 256, 256, 0, stream>>>(w, xt, yt, out);
}

// Round 7
// 59.103 us; speedup vs baseline: 2.5444x; 1.0887x over previous
//
#include <hip/hip_runtime.h>
#include <stdint.h>

// JAX reproduction (verified bit-exact R2/R4/R5/R6):
//   partitionable split: subkey[j] = threefry(key,0,j); bits[i] = fold o0^o1.
// R4: disjointness merged 5 streams -> 3 threefry/element.
// R5: intra-wave compaction: streams 34/5 only for 'hit' items (P~0.09).
// R7: no LDS table (cndmask chain, conflict-free); helper results via ballot
//     broadcast instead of LDS okb; 8 elements/thread.

#define N_TOTAL 16777216
#define Y_SIZE 16384 // COUT*R*C
#define X_SIZE 1024  // CIN*KH*KW

struct U2 { uint32_t a, b; };

// ---------- constexpr threefry (compile-time key derivation) ----------
constexpr uint32_t rotl_c(uint32_t x, int r) {
  return (x << r) | (x >> (32 - r));
}

constexpr U2 threefry_c(uint32_t k0, uint32_t k1, uint32_t x0, uint32_t x1) {
  uint32_t ks2 = k0 ^ k1 ^ 0x1BD11BDAu;
  x0 += k0; x1 += k1;
  x0 += x1; x1 = rotl_c(x1, 13); x1 ^= x0;
  x0 += x1; x1 = rotl_c(x1, 15); x1 ^= x0;
  x0 += x1; x1 = rotl_c(x1, 26); x1 ^= x0;
  x0 += x1; x1 = rotl_c(x1, 6);  x1 ^= x0;
  x0 += k1; x1 += ks2 + 1u;
  x0 += x1; x1 = rotl_c(x1, 17); x1 ^= x0;
  x0 += x1; x1 = rotl_c(x1, 29); x1 ^= x0;
  x0 += x1; x1 = rotl_c(x1, 16); x1 ^= x0;
  x0 += x1; x1 = rotl_c(x1, 24); x1 ^= x0;
  x0 += ks2; x1 += k0 + 2u;
  x0 += x1; x1 = rotl_c(x1, 13); x1 ^= x0;
  x0 += x1; x1 = rotl_c(x1, 15); x1 ^= x0;
  x0 += x1; x1 = rotl_c(x1, 26); x1 ^= x0;
  x0 += x1; x1 = rotl_c(x1, 6);  x1 ^= x0;
  x0 += k0; x1 += k1 + 3u;
  x0 += x1; x1 = rotl_c(x1, 17); x1 ^= x0;
  x0 += x1; x1 = rotl_c(x1, 29); x1 ^= x0;
  x0 += x1; x1 = rotl_c(x1, 16); x1 ^= x0;
  x0 += x1; x1 = rotl_c(x1, 24); x1 ^= x0;
  x0 += k1; x1 += ks2 + 4u;
  x0 += x1; x1 = rotl_c(x1, 13); x1 ^= x0;
  x0 += x1; x1 = rotl_c(x1, 15); x1 ^= x0;
  x0 += x1; x1 = rotl_c(x1, 26); x1 ^= x0;
  x0 += x1; x1 = rotl_c(x1, 6);  x1 ^= x0;
  x0 += ks2; x1 += k0 + 5u;
  return {x0, x1};
}

constexpr U2 SK1 = threefry_c(0u, 42u, 0u, 0u); // bern_plus
constexpr U2 SK2 = threefry_c(0u, 42u, 0u, 1u); // bern_minus
constexpr U2 SK3 = threefry_c(0u, 42u, 0u, 2u); // F_minus_raw
constexpr U2 SK4 = threefry_c(0u, 42u, 0u, 3u); // F_plus_raw
constexpr U2 SK5 = threefry_c(0u, 42u, 0u, 4u); // umin

constexpr uint32_t KS2_1 = SK1.a ^ SK1.b ^ 0x1BD11BDAu;
constexpr uint32_t KS2_2 = SK2.a ^ SK2.b ^ 0x1BD11BDAu;
constexpr uint32_t KS2_3 = SK3.a ^ SK3.b ^ 0x1BD11BDAu;
constexpr uint32_t KS2_4 = SK4.a ^ SK4.b ^ 0x1BD11BDAu;
constexpr uint32_t KS2_5 = SK5.a ^ SK5.b ^ 0x1BD11BDAu;

// u < p  <=>  bits < (ceil(p*2^23) << 9)   (exact)
constexpr uint32_t bern_thr(float pf) {
  double p8 = (double)pf * 8388608.0;
  uint64_t t = (uint64_t)p8;
  if ((double)t < p8) t += 1u;
  return (uint32_t)(t << 9);
}
constexpr uint32_t T_SEARCH  = bern_thr(0.032f);
constexpr uint32_t T_CAPTURE = bern_thr(0.102f);
constexpr uint32_t T_BACKOFF = bern_thr(0.96f);
constexpr uint32_t T_MINUS   = bern_thr(0.051f);
constexpr uint32_t T_UMIN    = bern_thr(0.008f);

__device__ __forceinline__ uint32_t rotl_d(uint32_t x, int r) {
  return __builtin_amdgcn_alignbit(x, x, 32 - r);
}

// threefry fold with precomputed ks2 (keys may be VGPR or SGPR)
__device__ __forceinline__ uint32_t tf_fold_k(uint32_t k0, uint32_t k1,
                                              uint32_t ks2, uint32_t ctr) {
  uint32_t x0 = k0;        // 0 + k0
  uint32_t x1 = ctr + k1;
  x0 += x1; x1 = rotl_d(x1, 13); x1 ^= x0;
  x0 += x1; x1 = rotl_d(x1, 15); x1 ^= x0;
  x0 += x1; x1 = rotl_d(x1, 26); x1 ^= x0;
  x0 += x1; x1 = rotl_d(x1, 6);  x1 ^= x0;
  x0 += k1; x1 += ks2 + 1u;
  x0 += x1; x1 = rotl_d(x1, 17); x1 ^= x0;
  x0 += x1; x1 = rotl_d(x1, 29); x1 ^= x0;
  x0 += x1; x1 = rotl_d(x1, 16); x1 ^= x0;
  x0 += x1; x1 = rotl_d(x1, 24); x1 ^= x0;
  x0 += ks2; x1 += k0 + 2u;
  x0 += x1; x1 = rotl_d(x1, 13); x1 ^= x0;
  x0 += x1; x1 = rotl_d(x1, 15); x1 ^= x0;
  x0 += x1; x1 = rotl_d(x1, 26); x1 ^= x0;
  x0 += x1; x1 = rotl_d(x1, 6);  x1 ^= x0;
  x0 += k0; x1 += k1 + 3u;
  x0 += x1; x1 = rotl_d(x1, 17); x1 ^= x0;
  x0 += x1; x1 = rotl_d(x1, 29); x1 ^= x0;
  x0 += x1; x1 = rotl_d(x1, 16); x1 ^= x0;
  x0 += x1; x1 = rotl_d(x1, 24); x1 ^= x0;
  x0 += k1; x1 += ks2 + 4u;
  x0 += x1; x1 = rotl_d(x1, 13); x1 ^= x0;
  x0 += x1; x1 = rotl_d(x1, 15); x1 ^= x0;
  x0 += x1; x1 = rotl_d(x1, 26); x1 ^= x0;
  x0 += x1; x1 = rotl_d(x1, 6);  x1 ^= x0;
  x0 += ks2; x1 += k0 + 5u;
  return x0 ^ x1;
}

__device__ __forceinline__ float bits_to_unit_float(uint32_t bits) {
  uint32_t fb = (bits >> 9) | 0x3f800000u;
  return __uint_as_float(fb) - 1.0f;
}

__device__ __forceinline__ uint32_t mbcnt64(uint64_t m) {
  return __builtin_amdgcn_mbcnt_hi((uint32_t)(m >> 32),
         __builtin_amdgcn_mbcnt_lo((uint32_t)m, 0u));
}

// F/umin streams for one hit item (identical float ops to reference)
__device__ __forceinline__ bool helper_ok(uint2 rc) {
  bool sm = (rc.x >> 31) != 0u;
  uint32_t ctr = rc.x & 0x7fffffffu;
  float wf = __uint_as_float(rc.y);
  const float inv7 = (float)(1.0 / 7.0);
  float ratio = __fmul_rn(wf, inv7);
  float thrF = sm
      ? __fmul_rn(__fsub_rn(1.0f, ratio), __fadd_rn(1.0f, ratio))  // pFm
      : __fmul_rn(ratio, __fsub_rn(2.0f, ratio));                  // pFp
  uint32_t k0 = sm ? SK3.a : SK4.a;
  uint32_t k1 = sm ? SK3.b : SK4.b;
  uint32_t ks = sm ? KS2_3 : KS2_4;
  uint32_t b34 = tf_fold_k(k0, k1, ks, ctr);
  uint32_t b5 = tf_fold_k(SK5.a, SK5.b, KS2_5, ctr);
  return (bits_to_unit_float(b34) < thrF) | (b5 < T_UMIN);
}

// ---------- precompute x_times (1024) and y_times (16384) ----------
__global__ void precompute_times(const int* __restrict__ in_sp,
                                 const int* __restrict__ out_sp,
                                 int* __restrict__ xt, int* __restrict__ yt) {
  int tid = blockIdx.x * 256 + threadIdx.x;
  if (tid < Y_SIZE) {
    int s = 0;
#pragma unroll
    for (int t = 0; t < 7; ++t) s += out_sp[t * Y_SIZE + tid];
    yt[tid] = 7 - s;
  } else if (tid < Y_SIZE + X_SIZE) {
    int j = tid - Y_SIZE;
    int s = 0;
#pragma unroll
    for (int t = 0; t < 7; ++t) s += in_sp[t * X_SIZE + j];
    xt[j] = 7 - s;
  }
}

// ---------- main kernel: 8 elem/thread; cndmask chain + ballot-broadcast ----
__global__ __launch_bounds__(256) void modstdp8(const float* __restrict__ w,
                                                const int* __restrict__ xt,
                                                const int* __restrict__ yt,
                                                float* __restrict__ out) {
  __shared__ uint2 rec[4 * 512];     // per-wave 512 slots: (ctr|selM<<31, wbits)
  __shared__ uint64_t okm[4 * 8];    // overflow-path masks (rarely used)

  uint32_t tid = threadIdx.x;
  uint32_t lane = tid & 63u;
  uint32_t ws = tid >> 6;
  uint32_t t = blockIdx.x * 256u + tid;
  uint32_t i0 = t * 8u;

  float4 wa = *reinterpret_cast<const float4*>(w + i0);
  float4 wb = *reinterpret_cast<const float4*>(w + i0 + 4u);
  int4 xa = *reinterpret_cast<const int4*>(xt + (i0 & 1023u));
  int4 xb = *reinterpret_cast<const int4*>(xt + (i0 & 1023u) + 4u);
  float warr[8];
  *reinterpret_cast<float4*>(warr) = wa;
  *reinterpret_cast<float4*>(warr + 4) = wb;
  int barr[8];
  *reinterpret_cast<int4*>(barr) = xa;
  *reinterpret_cast<int4*>(barr + 4) = xb;

  // 8 consecutive elements share cout,r,c -> one yt lookup
  uint32_t cout = (i0 >> 10) & 63u;
  uint32_t c = (i0 >> 16) & 15u;
  uint32_t r = i0 >> 20;
  int by = yt[cout * 256u + r * 16u + c];
  bool B = (by == 7);
  int mb6 = min(by, 6);

  bool hit[8], sM[8];
  uint32_t rank[8];
  uint32_t cnt = 0;

#pragma unroll
  for (int e = 0; e < 8; ++e) {
    uint32_t i = i0 + (uint32_t)e;
    int bx = barr[e];
    bool A = (bx == 7);
    // selM = !B && (A || Cg)  ==  !B && (bx > min(by,6))
    bool selm = (!B) && (bx > mb6);
    sM[e] = selm;
    uint32_t thr = selm ? (A ? T_BACKOFF : T_MINUS)
                        : (B ? (A ? 0u : T_SEARCH) : T_CAPTURE);
    uint32_t k0 = selm ? SK2.a : SK1.a;
    uint32_t k1 = selm ? SK2.b : SK1.b;
    uint32_t ks = selm ? KS2_2 : KS2_1;
    uint32_t bits12 = tf_fold_k(k0, k1, ks, i);
    bool h = bits12 < thr;
    hit[e] = h;

    uint64_t m = __ballot(h);
    uint32_t rk = 0;
    if (h) {
      rk = cnt + mbcnt64(m);
      rec[ws * 512u + rk] = make_uint2(i | (selm ? 0x80000000u : 0u),
                                       __float_as_uint(warr[e]));
    }
    rank[e] = rk;
    cnt += (uint32_t)__popcll(m);
  }

  // helper pass 0 (covers cnt <= 64, the ~always case)
  uint64_t okmask0;
  {
    bool ok = false;
    if (lane < cnt) ok = helper_ok(rec[ws * 512u + lane]);
    okmask0 = __ballot(ok);
  }

  if (__builtin_expect(cnt > 64u, 0)) {
    // rare wave-uniform overflow path: route all masks through LDS
    if (lane == 0u) okm[ws * 8u] = okmask0;
    for (uint32_t base = 64u; base < cnt; base += 64u) {
      bool ok = false;
      uint32_t idx = base + lane;
      if (idx < cnt) ok = helper_ok(rec[ws * 512u + idx]);
      uint64_t mm = __ballot(ok);
      if (lane == 0u) okm[ws * 8u + (base >> 6)] = mm;
    }
    float res[8];
#pragma unroll
    for (int e = 0; e < 8; ++e) {
      uint64_t mask = okm[ws * 8u + (rank[e] >> 6)];
      uint32_t ob = (uint32_t)(mask >> (rank[e] & 63u)) & 1u;
      float d = (hit[e] && ob) ? (sM[e] ? -1.0f : 1.0f) : 0.0f;
      res[e] = __builtin_amdgcn_fmed3f(warr[e] + d, 0.0f, 7.0f);
    }
    *reinterpret_cast<float4*>(out + i0) = *reinterpret_cast<float4*>(res);
    *reinterpret_cast<float4*>(out + i0 + 4u) =
        *reinterpret_cast<float4*>(res + 4);
  } else {
    float res[8];
#pragma unroll
    for (int e = 0; e < 8; ++e) {
      uint32_t ob = (uint32_t)(okmask0 >> rank[e]) & 1u;
      float d = (hit[e] && ob) ? (sM[e] ? -1.0f : 1.0f) : 0.0f;
      res[e] = __builtin_amdgcn_fmed3f(warr[e] + d, 0.0f, 7.0f);
    }
    *reinterpret_cast<float4*>(out + i0) = *reinterpret_cast<float4*>(res);
    *reinterpret_cast<float4*>(out + i0 + 4u) =
        *reinterpret_cast<float4*>(res + 4);
  }
}

extern "C" void kernel_launch(void* const* d_in, const int* in_sizes, int n_in,
                              void* d_out, int out_size, void* d_ws, size_t ws_size,
                              hipStream_t stream) {
  const float* w = (const float*)d_in[0];
  const int* isp = (const int*)d_in[1];
  const int* osp = (const int*)d_in[2];
  float* out = (float*)d_out;
  int* xt = (int*)d_ws;            // 1024 ints
  int* yt = ((int*)d_ws) + X_SIZE; // 16384 ints

  precompute_times<<<(Y_SIZE + X_SIZE + 255) / 256, 256, 0, stream>>>(isp, osp, xt, yt);
  modstdp8<<<N_TOTAL / 8 / 256, 256, 0, stream>>>(w, xt, yt, out);
}

// Round 8
// 58.126 us; speedup vs baseline: 2.5871x; 1.0168x over previous
//
#include <hip/hip_runtime.h>
#include <stdint.h>

// JAX reproduction (verified bit-exact R2/R4/R5/R6/R7):
//   partitionable split: subkey[j] = threefry(key,0,j); bits[i] = fold o0^o1.
// R4: disjointness merged 5 streams -> 3 threefry/element.
// R5: intra-wave compaction: streams 34/5 only for 'hit' items (P~0.09).
// R7: cndmask chain + ballot broadcast; 8 elem/thread.
// R8: helper-scatter: weights are ints 0..7 so non-hit out == w; helpers
//     compute the full updated value from a packed u32 record
//     (ctr|w<<24|selM<<27) and scatter it; owner readback deleted.

#define N_TOTAL 16777216
#define Y_SIZE 16384 // COUT*R*C
#define X_SIZE 1024  // CIN*KH*KW

struct U2 { uint32_t a, b; };

// ---------- constexpr threefry (compile-time key derivation) ----------
constexpr uint32_t rotl_c(uint32_t x, int r) {
  return (x << r) | (x >> (32 - r));
}

constexpr U2 threefry_c(uint32_t k0, uint32_t k1, uint32_t x0, uint32_t x1) {
  uint32_t ks2 = k0 ^ k1 ^ 0x1BD11BDAu;
  x0 += k0; x1 += k1;
  x0 += x1; x1 = rotl_c(x1, 13); x1 ^= x0;
  x0 += x1; x1 = rotl_c(x1, 15); x1 ^= x0;
  x0 += x1; x1 = rotl_c(x1, 26); x1 ^= x0;
  x0 += x1; x1 = rotl_c(x1, 6);  x1 ^= x0;
  x0 += k1; x1 += ks2 + 1u;
  x0 += x1; x1 = rotl_c(x1, 17); x1 ^= x0;
  x0 += x1; x1 = rotl_c(x1, 29); x1 ^= x0;
  x0 += x1; x1 = rotl_c(x1, 16); x1 ^= x0;
  x0 += x1; x1 = rotl_c(x1, 24); x1 ^= x0;
  x0 += ks2; x1 += k0 + 2u;
  x0 += x1; x1 = rotl_c(x1, 13); x1 ^= x0;
  x0 += x1; x1 = rotl_c(x1, 15); x1 ^= x0;
  x0 += x1; x1 = rotl_c(x1, 26); x1 ^= x0;
  x0 += x1; x1 = rotl_c(x1, 6);  x1 ^= x0;
  x0 += k0; x1 += k1 + 3u;
  x0 += x1; x1 = rotl_c(x1, 17); x1 ^= x0;
  x0 += x1; x1 = rotl_c(x1, 29); x1 ^= x0;
  x0 += x1; x1 = rotl_c(x1, 16); x1 ^= x0;
  x0 += x1; x1 = rotl_c(x1, 24); x1 ^= x0;
  x0 += k1; x1 += ks2 + 4u;
  x0 += x1; x1 = rotl_c(x1, 13); x1 ^= x0;
  x0 += x1; x1 = rotl_c(x1, 15); x1 ^= x0;
  x0 += x1; x1 = rotl_c(x1, 26); x1 ^= x0;
  x0 += x1; x1 = rotl_c(x1, 6);  x1 ^= x0;
  x0 += ks2; x1 += k0 + 5u;
  return {x0, x1};
}

constexpr U2 SK1 = threefry_c(0u, 42u, 0u, 0u); // bern_plus
constexpr U2 SK2 = threefry_c(0u, 42u, 0u, 1u); // bern_minus
constexpr U2 SK3 = threefry_c(0u, 42u, 0u, 2u); // F_minus_raw
constexpr U2 SK4 = threefry_c(0u, 42u, 0u, 3u); // F_plus_raw
constexpr U2 SK5 = threefry_c(0u, 42u, 0u, 4u); // umin

constexpr uint32_t KS2_1 = SK1.a ^ SK1.b ^ 0x1BD11BDAu;
constexpr uint32_t KS2_2 = SK2.a ^ SK2.b ^ 0x1BD11BDAu;
constexpr uint32_t KS2_3 = SK3.a ^ SK3.b ^ 0x1BD11BDAu;
constexpr uint32_t KS2_4 = SK4.a ^ SK4.b ^ 0x1BD11BDAu;
constexpr uint32_t KS2_5 = SK5.a ^ SK5.b ^ 0x1BD11BDAu;

// u < p  <=>  bits < (ceil(p*2^23) << 9)   (exact)
constexpr uint32_t bern_thr(float pf) {
  double p8 = (double)pf * 8388608.0;
  uint64_t t = (uint64_t)p8;
  if ((double)t < p8) t += 1u;
  return (uint32_t)(t << 9);
}
constexpr uint32_t T_SEARCH  = bern_thr(0.032f);
constexpr uint32_t T_CAPTURE = bern_thr(0.102f);
constexpr uint32_t T_BACKOFF = bern_thr(0.96f);
constexpr uint32_t T_MINUS   = bern_thr(0.051f);
constexpr uint32_t T_UMIN    = bern_thr(0.008f);

__device__ __forceinline__ uint32_t rotl_d(uint32_t x, int r) {
  return __builtin_amdgcn_alignbit(x, x, 32 - r);
}

// threefry fold with precomputed ks2 (keys may be VGPR or SGPR)
__device__ __forceinline__ uint32_t tf_fold_k(uint32_t k0, uint32_t k1,
                                              uint32_t ks2, uint32_t ctr) {
  uint32_t x0 = k0;        // 0 + k0
  uint32_t x1 = ctr + k1;
  x0 += x1; x1 = rotl_d(x1, 13); x1 ^= x0;
  x0 += x1; x1 = rotl_d(x1, 15); x1 ^= x0;
  x0 += x1; x1 = rotl_d(x1, 26); x1 ^= x0;
  x0 += x1; x1 = rotl_d(x1, 6);  x1 ^= x0;
  x0 += k1; x1 += ks2 + 1u;
  x0 += x1; x1 = rotl_d(x1, 17); x1 ^= x0;
  x0 += x1; x1 = rotl_d(x1, 29); x1 ^= x0;
  x0 += x1; x1 = rotl_d(x1, 16); x1 ^= x0;
  x0 += x1; x1 = rotl_d(x1, 24); x1 ^= x0;
  x0 += ks2; x1 += k0 + 2u;
  x0 += x1; x1 = rotl_d(x1, 13); x1 ^= x0;
  x0 += x1; x1 = rotl_d(x1, 15); x1 ^= x0;
  x0 += x1; x1 = rotl_d(x1, 26); x1 ^= x0;
  x0 += x1; x1 = rotl_d(x1, 6);  x1 ^= x0;
  x0 += k0; x1 += k1 + 3u;
  x0 += x1; x1 = rotl_d(x1, 17); x1 ^= x0;
  x0 += x1; x1 = rotl_d(x1, 29); x1 ^= x0;
  x0 += x1; x1 = rotl_d(x1, 16); x1 ^= x0;
  x0 += x1; x1 = rotl_d(x1, 24); x1 ^= x0;
  x0 += k1; x1 += ks2 + 4u;
  x0 += x1; x1 = rotl_d(x1, 13); x1 ^= x0;
  x0 += x1; x1 = rotl_d(x1, 15); x1 ^= x0;
  x0 += x1; x1 = rotl_d(x1, 26); x1 ^= x0;
  x0 += x1; x1 = rotl_d(x1, 6);  x1 ^= x0;
  x0 += ks2; x1 += k0 + 5u;
  return x0 ^ x1;
}

__device__ __forceinline__ float bits_to_unit_float(uint32_t bits) {
  uint32_t fb = (bits >> 9) | 0x3f800000u;
  return __uint_as_float(fb) - 1.0f;
}

__device__ __forceinline__ uint32_t mbcnt64(uint64_t m) {
  return __builtin_amdgcn_mbcnt_hi((uint32_t)(m >> 32),
         __builtin_amdgcn_mbcnt_lo((uint32_t)m, 0u));
}

// ---------- precompute x_times (1024) and y_times (16384) ----------
__global__ void precompute_times(const int* __restrict__ in_sp,
                                 const int* __restrict__ out_sp,
                                 int* __restrict__ xt, int* __restrict__ yt) {
  int tid = blockIdx.x * 256 + threadIdx.x;
  if (tid < Y_SIZE) {
    int s = 0;
#pragma unroll
    for (int t = 0; t < 7; ++t) s += out_sp[t * Y_SIZE + tid];
    yt[tid] = 7 - s;
  } else if (tid < Y_SIZE + X_SIZE) {
    int j = tid - Y_SIZE;
    int s = 0;
#pragma unroll
    for (int t = 0; t < 7; ++t) s += in_sp[t * X_SIZE + j];
    xt[j] = 7 - s;
  }
}

// ---------- main kernel: 8 elem/thread; helper-scatter, no readback ----------
__global__ __launch_bounds__(256) void modstdp8s(const float* __restrict__ w,
                                                 const int* __restrict__ xt,
                                                 const int* __restrict__ yt,
                                                 float* __restrict__ out) {
  __shared__ uint32_t rec[4 * 512]; // per-wave 512 slots: ctr|w<<24|selM<<27

  uint32_t tid = threadIdx.x;
  uint32_t lane = tid & 63u;
  uint32_t ws = tid >> 6;
  uint32_t t = blockIdx.x * 256u + tid;
  uint32_t i0 = t * 8u;

  float4 wa = *reinterpret_cast<const float4*>(w + i0);
  float4 wb = *reinterpret_cast<const float4*>(w + i0 + 4u);
  int4 xa = *reinterpret_cast<const int4*>(xt + (i0 & 1023u));
  int4 xb = *reinterpret_cast<const int4*>(xt + (i0 & 1023u) + 4u);
  float warr[8];
  *reinterpret_cast<float4*>(warr) = wa;
  *reinterpret_cast<float4*>(warr + 4) = wb;
  int barr[8];
  *reinterpret_cast<int4*>(barr) = xa;
  *reinterpret_cast<int4*>(barr + 4) = xb;

  // 8 consecutive elements share cout,r,c -> one yt lookup
  uint32_t cout = (i0 >> 10) & 63u;
  uint32_t c = (i0 >> 16) & 15u;
  uint32_t r = i0 >> 20;
  int by = yt[cout * 256u + r * 16u + c];
  bool B = (by == 7);
  // selM = !B && (bx > min(by,6)): fold !B into the gate (bx<=7 < 8)
  int gate = B ? 8 : min(by, 6);
  // thr for the non-selM branch: B ? (A?0:SEARCH) : CAPTURE  (when !B, !selM
  // implies bx<7 i.e. !A, so CAPTURE covers both A-slots)
  uint32_t tNS_A = B ? 0u : T_CAPTURE;
  uint32_t tNS_nA = B ? T_SEARCH : T_CAPTURE;

  uint32_t cnt = 0;

#pragma unroll
  for (int e = 0; e < 8; ++e) {
    uint32_t i = i0 + (uint32_t)e;
    int bx = barr[e];
    bool A = (bx == 7);
    bool selm = bx > gate;
    uint32_t tS = A ? T_BACKOFF : T_MINUS;
    uint32_t tN = A ? tNS_A : tNS_nA;
    uint32_t thr = selm ? tS : tN;
    uint32_t k0 = selm ? SK2.a : SK1.a;
    uint32_t k1 = selm ? SK2.b : SK1.b;
    uint32_t ks = selm ? KS2_2 : KS2_1;
    uint32_t bits12 = tf_fold_k(k0, k1, ks, i);
    bool h = bits12 < thr;

    uint64_t m = __ballot(h);
    if (h) {
      uint32_t rk = cnt + mbcnt64(m);
      uint32_t wi = (uint32_t)warr[e]; // weights are exact ints 0..7
      rec[ws * 512u + rk] = i | (wi << 24) | (selm ? 0x08000000u : 0u);
    }
    cnt += (uint32_t)__popcll(m);
  }

  // bulk store: non-hit outputs are exactly w (ints 0..7, clip is a no-op)
  *reinterpret_cast<float4*>(out + i0) = wa;
  *reinterpret_cast<float4*>(out + i0 + 4u) = wb;

  // order bulk stores before helper scatter stores (same-wave, same address)
  asm volatile("s_waitcnt vmcnt(0)" ::: "memory");

  // helpers: lanes 0..cnt-1 finish one hit item each and scatter the result
  for (uint32_t base = 0; base < cnt; base += 64u) {
    uint32_t idx = base + lane;
    if (idx < cnt) {
      uint32_t rc = rec[ws * 512u + idx];
      uint32_t ctr = rc & 0x00FFFFFFu;
      uint32_t wi = (rc >> 24) & 7u;
      bool sm = (rc & 0x08000000u) != 0u;
      float wf = (float)wi;

      const float inv7 = (float)(1.0 / 7.0);
      float ratio = __fmul_rn(wf, inv7);
      float thrF = sm
          ? __fmul_rn(__fsub_rn(1.0f, ratio), __fadd_rn(1.0f, ratio))  // pFm
          : __fmul_rn(ratio, __fsub_rn(2.0f, ratio));                  // pFp
      uint32_t k0 = sm ? SK3.a : SK4.a;
      uint32_t k1 = sm ? SK3.b : SK4.b;
      uint32_t ks = sm ? KS2_3 : KS2_4;
      uint32_t b34 = tf_fold_k(k0, k1, ks, ctr);
      uint32_t b5 = tf_fold_k(SK5.a, SK5.b, KS2_5, ctr);
      bool ok = (bits_to_unit_float(b34) < thrF) | (b5 < T_UMIN);
      if (ok) {
        int nw = sm ? (int)wi - 1 : (int)wi + 1;
        nw = max(min(nw, 7), 0);
        out[ctr] = (float)nw;
      }
    }
  }
}

extern "C" void kernel_launch(void* const* d_in, const int* in_sizes, int n_in,
                              void* d_out, int out_size, void* d_ws, size_t ws_size,
                              hipStream_t stream) {
  const float* w = (const float*)d_in[0];
  const int* isp = (const int*)d_in[1];
  const int* osp = (const int*)d_in[2];
  float* out = (float*)d_out;
  int* xt = (int*)d_ws;            // 1024 ints
  int* yt = ((int*)d_ws) + X_SIZE; // 16384 ints

  precompute_times<<<(Y_SIZE + X_SIZE + 255) / 256, 256, 0, stream>>>(isp, osp, xt, yt);
  modstdp8s<<<N_TOTAL / 8 / 256, 256, 0, stream>>>(w, xt, yt, out);
}